// Round 2
// baseline (543.077 us; speedup 1.0000x reference)
//
#include <hip/hip_runtime.h>
#include <hip/hip_bf16.h>

#define NN 50000
#define EE 600000
#define HH 128
#define OUTD 32
#define RR 64
#define BB 16
#define KK 2048   // BB*HH
#define NPB 16    // nodes per fused block
#define STRB 4144 // LDS agg row stride bytes (2048*2 + 48; 16B-aligned, 8-bank spread)

typedef short s16x8 __attribute__((ext_vector_type(8)));
typedef float f32x4 __attribute__((ext_vector_type(4)));
typedef unsigned short ushort_t;
typedef unsigned int uint_t;

__device__ inline ushort_t f_to_bf16(float f){
    __hip_bfloat16 h = __float2bfloat16(f);
    return *reinterpret_cast<ushort_t*>(&h);
}
__device__ inline uint_t pack_bf16x2(float a, float b){
    return (uint_t)f_to_bf16(a) | ((uint_t)f_to_bf16(b) << 16);
}

__global__ void zero_i32(int* p, int n){
    int i = blockIdx.x*256 + threadIdx.x;
    if (i < n) p[i] = 0;
}

__global__ void hist_kernel(const int* __restrict__ dst, int* counts){
    int e = blockIdx.x*256 + threadIdx.x;
    if (e < EE) atomicAdd(&counts[dst[e]], 1);
}

// single-block inclusive scan over counts -> offsets[1..N], offsets[0]=0
__global__ void scan_kernel(const int* __restrict__ counts, int* __restrict__ offsets){
    __shared__ int wsum[16];
    __shared__ int carryS;
    int t = threadIdx.x;
    int lane = t & 63, wv = t >> 6;
    if (t == 0){ carryS = 0; offsets[0] = 0; }
    __syncthreads();
    for (int base = 0; base < NN; base += 1024){
        int v = (base + t < NN) ? counts[base + t] : 0;
        int x = v;
        #pragma unroll
        for (int off = 1; off < 64; off <<= 1){
            int y = __shfl_up(x, off, 64);
            if (lane >= off) x += y;
        }
        if (lane == 63) wsum[wv] = x;
        __syncthreads();
        int wpre = 0;
        for (int i = 0; i < wv; i++) wpre += wsum[i];
        int incl = carryS + wpre + x;
        if (base + t < NN) offsets[base + t + 1] = incl;
        __syncthreads();
        if (t == 1023) carryS = incl;
        __syncthreads();
    }
}

// scatter edge payload sorted by dst: meta[p] = {src, etype, norm_bits, 0}
__global__ void scatter_kernel(const int* __restrict__ dst, const int* __restrict__ src,
                               const int* __restrict__ etype, const float* __restrict__ norm,
                               const int* __restrict__ offsets, int* cursor,
                               int4* __restrict__ meta){
    int e = blockIdx.x*256 + threadIdx.x;
    if (e >= EE) return;
    int d = dst[e];
    int r = atomicAdd(&cursor[d], 1);
    int4 m;
    m.x = src[e];
    m.y = etype[e];
    m.z = __float_as_int(norm[e]);
    m.w = 0;
    meta[offsets[d] + r] = m;
}

// transposed bf16 weights: Wt1[o][k] = V1[k][o] (k = b*H+i), Wt2[o][k] = V2[k][o]
__global__ void convw_kernel(const float* __restrict__ V1, const float* __restrict__ V2,
                             ushort_t* __restrict__ Wt1, ushort_t* __restrict__ Wt2){
    int i = blockIdx.x*256 + threadIdx.x;
    if (i < HH*KK){
        int o = i / KK, k = i % KK;
        Wt1[i] = f_to_bf16(V1[(size_t)k*HH + o]);
    } else {
        int j = i - HH*KK;
        if (j < OUTD*KK){
            int o = j / KK, k = j % KK;
            Wt2[j] = f_to_bf16(V2[(size_t)k*OUTD + o]);
        }
    }
}

// Fused: aggregate 16 nodes into LDS bf16 tile, then MFMA against Wt.
// NOUT==128: wave w computes output col-tile w (16 cols), K=2048 full.
// NOUT==32:  wave w -> (ntile = w&1, kpart = w>>1), partials reduced in LDS.
template<bool IN_BF16, int NOUT, bool RELU, bool OUT_BF16>
__global__ __launch_bounds__(512) void fused_layer(
    const void* __restrict__ xin, const int4* __restrict__ meta,
    const int* __restrict__ offsets, const float* __restrict__ comp,
    const ushort_t* __restrict__ Wt, const float* __restrict__ bias,
    void* __restrict__ yout)
{
    __shared__ char aggS[NPB * STRB];
    __shared__ float compS[RR * BB];
    __shared__ float partS[NOUT == 32 ? 8 * 256 : 1];

    int tid = threadIdx.x;
    int w = tid >> 6, lane = tid & 63;
    for (int i = tid; i < RR*BB; i += 512) compS[i] = comp[i];
    __syncthreads();

    int v0 = blockIdx.x * NPB;

    // ---- gather phase: wave w owns local rows 2w, 2w+1 ----
    #pragma unroll
    for (int ri = 0; ri < 2; ++ri){
        int r = 2*w + ri;
        int v = v0 + r;
        float a0[BB], a1[BB];
        #pragma unroll
        for (int b = 0; b < BB; b++){ a0[b] = 0.f; a1[b] = 0.f; }
        if (v < NN){
            int p = offsets[v], end = offsets[v+1];
            // pair-unrolled: two independent gathers in flight
            for (; p + 1 < end; p += 2){
                int4 m0 = meta[p];
                int4 m1 = meta[p+1];
                float x00, x01, x10, x11;
                if (IN_BF16){
                    uint_t u0 = *reinterpret_cast<const uint_t*>(
                        reinterpret_cast<const ushort_t*>(xin) + (size_t)m0.x*HH + 2*lane);
                    uint_t u1 = *reinterpret_cast<const uint_t*>(
                        reinterpret_cast<const ushort_t*>(xin) + (size_t)m1.x*HH + 2*lane);
                    x00 = __uint_as_float((u0 & 0xffffu) << 16);
                    x01 = __uint_as_float(u0 & 0xffff0000u);
                    x10 = __uint_as_float((u1 & 0xffffu) << 16);
                    x11 = __uint_as_float(u1 & 0xffff0000u);
                } else {
                    float2 f0 = *reinterpret_cast<const float2*>(
                        reinterpret_cast<const float*>(xin) + (size_t)m0.x*HH + 2*lane);
                    float2 f1 = *reinterpret_cast<const float2*>(
                        reinterpret_cast<const float*>(xin) + (size_t)m1.x*HH + 2*lane);
                    x00 = f0.x; x01 = f0.y; x10 = f1.x; x11 = f1.y;
                }
                float n0 = __int_as_float(m0.z), n1 = __int_as_float(m1.z);
                const float* c0 = &compS[m0.y * BB];
                const float* c1 = &compS[m1.y * BB];
                #pragma unroll
                for (int b = 0; b < BB; b++){
                    float w0 = c0[b] * n0, w1 = c1[b] * n1;
                    a0[b] = fmaf(w0, x00, a0[b]);
                    a1[b] = fmaf(w0, x01, a1[b]);
                    a0[b] = fmaf(w1, x10, a0[b]);
                    a1[b] = fmaf(w1, x11, a1[b]);
                }
            }
            if (p < end){
                int4 m0 = meta[p];
                float x00, x01;
                if (IN_BF16){
                    uint_t u0 = *reinterpret_cast<const uint_t*>(
                        reinterpret_cast<const ushort_t*>(xin) + (size_t)m0.x*HH + 2*lane);
                    x00 = __uint_as_float((u0 & 0xffffu) << 16);
                    x01 = __uint_as_float(u0 & 0xffff0000u);
                } else {
                    float2 f0 = *reinterpret_cast<const float2*>(
                        reinterpret_cast<const float*>(xin) + (size_t)m0.x*HH + 2*lane);
                    x00 = f0.x; x01 = f0.y;
                }
                float n0 = __int_as_float(m0.z);
                const float* c0 = &compS[m0.y * BB];
                #pragma unroll
                for (int b = 0; b < BB; b++){
                    float w0 = c0[b] * n0;
                    a0[b] = fmaf(w0, x00, a0[b]);
                    a1[b] = fmaf(w0, x01, a1[b]);
                }
            }
        }
        // write LDS row r: agg[r][b*128 + 2*lane] packed bf16x2
        char* rowp = aggS + r * STRB;
        #pragma unroll
        for (int b = 0; b < BB; b++){
            *reinterpret_cast<uint_t*>(rowp + b*256 + lane*4) = pack_bf16x2(a0[b], a1[b]);
        }
    }
    __syncthreads();

    // ---- GEMM phase ----
    int arow = lane & 15;
    int kc = (lane >> 4) * 8;
    if (NOUT == HH){
        f32x4 acc;
        #pragma unroll
        for (int j = 0; j < 4; j++) acc[j] = 0.f;
        const ushort_t* wrow = Wt + (size_t)(w*16 + (lane & 15)) * KK;
        for (int k0 = 0; k0 < KK; k0 += 32){
            s16x8 a = *reinterpret_cast<const s16x8*>(aggS + arow*STRB + (k0 + kc)*2);
            s16x8 b = *reinterpret_cast<const s16x8*>(wrow + k0 + kc);
            acc = __builtin_amdgcn_mfma_f32_16x16x32_bf16(a, b, acc, 0, 0, 0);
        }
        int rbase = (lane >> 4) << 2;
        int col = w*16 + (lane & 15);
        float bv = bias[col];
        #pragma unroll
        for (int r = 0; r < 4; r++){
            int node = v0 + rbase + r;
            if (node < NN){
                float val = acc[r] + bv;
                if (RELU) val = fmaxf(val, 0.f);
                if (OUT_BF16)
                    reinterpret_cast<ushort_t*>(yout)[(size_t)node*NOUT + col] = f_to_bf16(val);
                else
                    reinterpret_cast<float*>(yout)[(size_t)node*NOUT + col] = val;
            }
        }
    } else {
        // NOUT==32: nt = w&1, kp = w>>1 (4 K-partitions of 512)
        f32x4 acc;
        #pragma unroll
        for (int j = 0; j < 4; j++) acc[j] = 0.f;
        int nt = w & 1, kp = w >> 1;
        const ushort_t* wrow = Wt + (size_t)(nt*16 + (lane & 15)) * KK;
        int kbeg = kp * 512;
        for (int k0 = kbeg; k0 < kbeg + 512; k0 += 32){
            s16x8 a = *reinterpret_cast<const s16x8*>(aggS + arow*STRB + (k0 + kc)*2);
            s16x8 b = *reinterpret_cast<const s16x8*>(wrow + k0 + kc);
            acc = __builtin_amdgcn_mfma_f32_16x16x32_bf16(a, b, acc, 0, 0, 0);
        }
        #pragma unroll
        for (int r = 0; r < 4; r++){
            int idx = (((lane >> 4) << 2) + r)*16 + (lane & 15);
            partS[w*256 + idx] = acc[r];
        }
        __syncthreads();
        int nt2 = tid >> 8, idx = tid & 255;
        float s = 0.f;
        #pragma unroll
        for (int kp2 = 0; kp2 < 4; kp2++) s += partS[(kp2*2 + nt2)*256 + idx];
        int row = idx >> 4, col = nt2*16 + (idx & 15);
        int node = v0 + row;
        if (node < NN){
            float val = s + bias[col];
            if (RELU) val = fmaxf(val, 0.f);
            reinterpret_cast<float*>(yout)[(size_t)node*OUTD + col] = val;
        }
    }
}

extern "C" void kernel_launch(void* const* d_in, const int* in_sizes, int n_in,
                              void* d_out, int out_size, void* d_ws, size_t ws_size,
                              hipStream_t stream){
    const int*   src   = (const int*)d_in[0];
    const int*   dst   = (const int*)d_in[1];
    const int*   etype = (const int*)d_in[2];
    const float* norm  = (const float*)d_in[3];
    const float* emb   = (const float*)d_in[4];
    const float* V1    = (const float*)d_in[5];
    const float* comp1 = (const float*)d_in[6];
    const float* bias1 = (const float*)d_in[7];
    const float* V2    = (const float*)d_in[8];
    const float* comp2 = (const float*)d_in[9];
    const float* bias2 = (const float*)d_in[10];
    float* out = (float*)d_out;

    char* w = (char*)d_ws;
    auto alloc = [&](size_t bytes) -> char* {
        char* p = w; w += (bytes + 255) & ~(size_t)255; return p;
    };
    int*      offsets = (int*)alloc((NN + 1) * 4);
    int*      counts  = (int*)alloc(NN * 4);
    int*      cursor  = (int*)alloc(NN * 4);
    int4*     meta    = (int4*)alloc((size_t)EE * 16);
    ushort_t* Wt1     = (ushort_t*)alloc((size_t)HH * KK * 2);
    ushort_t* Wt2     = (ushort_t*)alloc((size_t)OUTD * KK * 2);
    ushort_t* h       = (ushort_t*)alloc((size_t)NN * HH * 2);

    // CSR build + sorted payload
    zero_i32<<<(NN + 255)/256, 256, 0, stream>>>(counts, NN);
    zero_i32<<<(NN + 255)/256, 256, 0, stream>>>(cursor, NN);
    hist_kernel<<<(EE + 255)/256, 256, 0, stream>>>(dst, counts);
    scan_kernel<<<1, 1024, 0, stream>>>(counts, offsets);
    scatter_kernel<<<(EE + 255)/256, 256, 0, stream>>>(dst, src, etype, norm,
                                                       offsets, cursor, meta);
    convw_kernel<<<((HH + OUTD)*KK + 255)/256, 256, 0, stream>>>(V1, V2, Wt1, Wt2);

    int nblocks = (NN + NPB - 1) / NPB;
    // layer 1: emb (f32) -> h (bf16, relu)
    fused_layer<false, HH, true, true><<<nblocks, 512, 0, stream>>>(
        emb, meta, offsets, comp1, Wt1, bias1, h);
    // layer 2: h (bf16) -> out (f32)
    fused_layer<true, OUTD, false, false><<<nblocks, 512, 0, stream>>>(
        h, meta, offsets, comp2, Wt2, bias2, out);
}

// Round 3
// 426.322 us; speedup vs baseline: 1.2739x; 1.2739x over previous
//
#include <hip/hip_runtime.h>
#include <hip/hip_bf16.h>

#define NN 50000
#define EE 600000
#define HH 128
#define OUTD 32
#define RR 64
#define BB 16
#define KK 2048   // BB*HH
#define NPB 16    // nodes per fused block (50000 = 16 * 3125 exactly)
#define STRB 4112 // LDS agg row stride bytes (4096+16): conflict-free MFMA A reads
#define SC_B ((NN + 1023) / 1024)  // 49 scan chunks

typedef short s16x8 __attribute__((ext_vector_type(8)));
typedef float f32x4 __attribute__((ext_vector_type(4)));
typedef unsigned short ushort_t;
typedef unsigned int uint_t;

__device__ inline ushort_t f_to_bf16(float f){
    __hip_bfloat16 h = __float2bfloat16(f);
    return *reinterpret_cast<ushort_t*>(&h);
}
__device__ inline uint_t pack_bf16x2(float a, float b){
    return (uint_t)f_to_bf16(a) | ((uint_t)f_to_bf16(b) << 16);
}
__device__ inline float bf16_lo(uint_t u){ return __uint_as_float(u << 16); }
__device__ inline float bf16_hi(uint_t u){ return __uint_as_float(u & 0xffff0000u); }

__global__ void zero_i32(int* p, int n){
    int i = blockIdx.x*256 + threadIdx.x;
    if (i < n) p[i] = 0;
}

__global__ void hist_kernel(const int* __restrict__ dst, int* counts){
    int e = blockIdx.x*256 + threadIdx.x;
    if (e < EE) atomicAdd(&counts[dst[e]], 1);
}

// ---- hierarchical scan: chunk totals -> scan totals -> final ----
__global__ void scan_part(const int* __restrict__ counts, int* __restrict__ tot){
    int b = blockIdx.x, t = threadIdx.x;
    int i0 = b*1024 + t*4;
    int s = 0;
    if (i0 + 3 < NN){
        int4 v = *reinterpret_cast<const int4*>(&counts[i0]);
        s = v.x + v.y + v.z + v.w;
    } else {
        for (int j = 0; j < 4; j++) if (i0 + j < NN) s += counts[i0 + j];
    }
    #pragma unroll
    for (int off = 32; off; off >>= 1) s += __shfl_xor(s, off, 64);
    __shared__ int ws[4];
    if ((t & 63) == 0) ws[t >> 6] = s;
    __syncthreads();
    if (t == 0) tot[b] = ws[0] + ws[1] + ws[2] + ws[3];
}

__global__ void scan_tot(int* tot){  // 1 block, 64 threads (SC_B <= 64)
    int t = threadIdx.x;
    int v = (t < SC_B) ? tot[t] : 0;
    int x = v;
    #pragma unroll
    for (int off = 1; off < 64; off <<= 1){
        int y = __shfl_up(x, off, 64);
        if (t >= off) x += y;
    }
    if (t < SC_B) tot[t] = x - v;  // exclusive base per chunk
}

__global__ void scan_final(const int* __restrict__ counts, const int* __restrict__ tot,
                           int* __restrict__ offsets, int* __restrict__ cursor){
    int b = blockIdx.x, t = threadIdx.x, lane = t & 63, wv = t >> 6;
    int i0 = b*1024 + t*4;
    int v[4]; int s = 0;
    #pragma unroll
    for (int j = 0; j < 4; j++){ v[j] = (i0 + j < NN) ? counts[i0 + j] : 0; s += v[j]; }
    int x = s;
    #pragma unroll
    for (int off = 1; off < 64; off <<= 1){
        int y = __shfl_up(x, off, 64);
        if (lane >= off) x += y;
    }
    __shared__ int ws[4];
    if (lane == 63) ws[wv] = x;
    __syncthreads();
    int pre = tot[b];
    for (int i = 0; i < wv; i++) pre += ws[i];
    int run = pre + x - s;  // exclusive start of this thread's 4 elems
    #pragma unroll
    for (int j = 0; j < 4; j++){
        if (i0 + j < NN){
            cursor[i0 + j] = run;
            offsets[i0 + j + 1] = run + v[j];
        }
        run += v[j];
    }
    if (b == 0 && t == 0) offsets[0] = 0;
}

// scatter edge payload sorted by dst: meta[r] = {src, etype, norm_bits, 0}
__global__ void scatter_kernel(const int* __restrict__ dst, const int* __restrict__ src,
                               const int* __restrict__ etype, const float* __restrict__ norm,
                               int* cursor, int4* __restrict__ meta){
    int e = blockIdx.x*256 + threadIdx.x;
    if (e >= EE) return;
    int d = dst[e];
    int r = atomicAdd(&cursor[d], 1);
    int4 m;
    m.x = src[e];
    m.y = etype[e];
    m.z = __float_as_int(norm[e]);
    m.w = 0;
    meta[r] = m;
}

// transposed bf16 weights: Wt1[o][k] = V1[k][o] (k = b*H+i), Wt2[o][k] = V2[k][o]
__global__ void convw_kernel(const float* __restrict__ V1, const float* __restrict__ V2,
                             ushort_t* __restrict__ Wt1, ushort_t* __restrict__ Wt2){
    int i = blockIdx.x*256 + threadIdx.x;
    if (i < HH*KK){
        int o = i / KK, k = i % KK;
        Wt1[i] = f_to_bf16(V1[(size_t)k*HH + o]);
    } else {
        int j = i - HH*KK;
        if (j < OUTD*KK){
            int o = j / KK, k = j % KK;
            Wt2[j] = f_to_bf16(V2[(size_t)k*OUTD + o]);
        }
    }
}

__global__ void conv_emb(const float* __restrict__ emb, ushort_t* __restrict__ xb){
    int i = blockIdx.x*256 + threadIdx.x;
    if (i < NN*HH/2){
        float2 f = *reinterpret_cast<const float2*>(emb + 2*(size_t)i);
        *reinterpret_cast<uint_t*>(xb + 2*(size_t)i) = pack_bf16x2(f.x, f.y);
    }
}

// Fused per 16 nodes: 16 waves, wave w gathers node v0+w into LDS bf16 row,
// then MFMA vs Wt. NOUT=128: wave -> (ct=w&7, kp=w>>3), K halves, reduce via LDS.
// NOUT=32: wave -> (nt=w&1, kp=w>>1), K eighths, reduce via LDS.
template<int NOUT, bool RELU, bool OUT_BF16>
__global__ __launch_bounds__(1024, 8) void fused_layer(
    const ushort_t* __restrict__ xin, const int4* __restrict__ meta,
    const int* __restrict__ offsets, const float* __restrict__ comp,
    const ushort_t* __restrict__ Wt, const float* __restrict__ bias,
    void* __restrict__ yout)
{
    __shared__ __align__(16) char aggS[NPB * STRB];

    int tid = threadIdx.x;
    int w = tid >> 6, lane = tid & 63;
    int v0 = blockIdx.x * NPB;
    int v = v0 + w;   // always < NN (50000 = 16*3125)

    // ---- gather: wave w owns node v; all edge metadata is wave-uniform ----
    float a0[BB], a1[BB];
    #pragma unroll
    for (int b = 0; b < BB; b++){ a0[b] = 0.f; a1[b] = 0.f; }
    {
        int p = offsets[v], end = offsets[v+1];
        for (; p + 1 < end; p += 2){
            int4 m0 = meta[p];
            int4 m1 = meta[p+1];
            int  s0 = __builtin_amdgcn_readfirstlane(m0.x);
            int  e0 = __builtin_amdgcn_readfirstlane(m0.y);
            float n0 = __int_as_float(__builtin_amdgcn_readfirstlane(m0.z));
            int  s1 = __builtin_amdgcn_readfirstlane(m1.x);
            int  e1 = __builtin_amdgcn_readfirstlane(m1.y);
            float n1 = __int_as_float(__builtin_amdgcn_readfirstlane(m1.z));
            uint_t u0 = *reinterpret_cast<const uint_t*>(xin + (size_t)s0*HH + 2*lane);
            uint_t u1 = *reinterpret_cast<const uint_t*>(xin + (size_t)s1*HH + 2*lane);
            const float* c0 = comp + e0*BB;   // SGPR base -> scalar loads
            const float* c1 = comp + e1*BB;
            float xa0 = bf16_lo(u0)*n0, xb0 = bf16_hi(u0)*n0;
            float xa1 = bf16_lo(u1)*n1, xb1 = bf16_hi(u1)*n1;
            #pragma unroll
            for (int b = 0; b < BB; b++){
                a0[b] = fmaf(c0[b], xa0, a0[b]);
                a1[b] = fmaf(c0[b], xb0, a1[b]);
                a0[b] = fmaf(c1[b], xa1, a0[b]);
                a1[b] = fmaf(c1[b], xb1, a1[b]);
            }
        }
        if (p < end){
            int4 m0 = meta[p];
            int  s0 = __builtin_amdgcn_readfirstlane(m0.x);
            int  e0 = __builtin_amdgcn_readfirstlane(m0.y);
            float n0 = __int_as_float(__builtin_amdgcn_readfirstlane(m0.z));
            uint_t u0 = *reinterpret_cast<const uint_t*>(xin + (size_t)s0*HH + 2*lane);
            const float* c0 = comp + e0*BB;
            float xa0 = bf16_lo(u0)*n0, xb0 = bf16_hi(u0)*n0;
            #pragma unroll
            for (int b = 0; b < BB; b++){
                a0[b] = fmaf(c0[b], xa0, a0[b]);
                a1[b] = fmaf(c0[b], xb0, a1[b]);
            }
        }
    }
    // LDS row w: agg[w][b*128 + 2*lane..+1] packed bf16x2
    {
        char* rowp = aggS + w * STRB;
        #pragma unroll
        for (int b = 0; b < BB; b++)
            *reinterpret_cast<uint_t*>(rowp + b*256 + lane*4) = pack_bf16x2(a0[b], a1[b]);
    }
    __syncthreads();

    // ---- GEMM phase ----
    int lane15 = lane & 15;
    int kc = (lane >> 4) * 8;
    float* partS = reinterpret_cast<float*>(aggS);  // aliased AFTER MFMA reads + sync

    if (NOUT == HH){
        int ct = w & 7, kp = w >> 3;           // 8 col-tiles x 2 K-halves (K=1024)
        f32x4 acc;
        #pragma unroll
        for (int j = 0; j < 4; j++) acc[j] = 0.f;
        const ushort_t* wrow = Wt + (size_t)(ct*16 + lane15)*KK + kp*1024 + kc;
        const char* ap = aggS + lane15*STRB + (kp*1024 + kc)*2;
        #pragma unroll 4
        for (int k = 0; k < 1024; k += 32){
            s16x8 a = *reinterpret_cast<const s16x8*>(ap + k*2);
            s16x8 b = *reinterpret_cast<const s16x8*>(wrow + k);
            acc = __builtin_amdgcn_mfma_f32_16x16x32_bf16(a, b, acc, 0, 0, 0);
        }
        __syncthreads();
        if (kp == 1){
            #pragma unroll
            for (int r = 0; r < 4; r++){
                int idx = ((lane >> 4)*4 + r)*16 + lane15;
                partS[ct*256 + idx] = acc[r];
            }
        }
        __syncthreads();
        if (kp == 0){
            int col = ct*16 + lane15;
            float bv = bias[col];
            #pragma unroll
            for (int r = 0; r < 4; r++){
                int row = (lane >> 4)*4 + r;
                int idx = row*16 + lane15;
                float val = acc[r] + partS[ct*256 + idx] + bv;
                if (RELU) val = fmaxf(val, 0.f);
                if (OUT_BF16)
                    reinterpret_cast<ushort_t*>(yout)[(size_t)(v0 + row)*NOUT + col] = f_to_bf16(val);
                else
                    reinterpret_cast<float*>(yout)[(size_t)(v0 + row)*NOUT + col] = val;
            }
        }
    } else {
        int nt = w & 1, kp = w >> 1;           // 2 col-tiles x 8 K-parts (K=256)
        f32x4 acc;
        #pragma unroll
        for (int j = 0; j < 4; j++) acc[j] = 0.f;
        const ushort_t* wrow = Wt + (size_t)(nt*16 + lane15)*KK + kp*256 + kc;
        const char* ap = aggS + lane15*STRB + (kp*256 + kc)*2;
        #pragma unroll
        for (int k = 0; k < 256; k += 32){
            s16x8 a = *reinterpret_cast<const s16x8*>(ap + k*2);
            s16x8 b = *reinterpret_cast<const s16x8*>(wrow + k);
            acc = __builtin_amdgcn_mfma_f32_16x16x32_bf16(a, b, acc, 0, 0, 0);
        }
        __syncthreads();
        #pragma unroll
        for (int r = 0; r < 4; r++){
            int idx = ((lane >> 4)*4 + r)*16 + lane15;
            partS[w*256 + idx] = acc[r];   // w == kp*2 + nt
        }
        __syncthreads();
        if (tid < 512){
            int nt2 = tid >> 8, idx = tid & 255;
            int col = nt2*16 + (idx & 15);
            float s = bias[col];
            #pragma unroll
            for (int kp2 = 0; kp2 < 8; kp2++) s += partS[(kp2*2 + nt2)*256 + idx];
            if (RELU) s = fmaxf(s, 0.f);
            int node = v0 + (idx >> 4);
            if (OUT_BF16)
                reinterpret_cast<ushort_t*>(yout)[(size_t)node*NOUT + col] = f_to_bf16(s);
            else
                reinterpret_cast<float*>(yout)[(size_t)node*NOUT + col] = s;
        }
    }
}

extern "C" void kernel_launch(void* const* d_in, const int* in_sizes, int n_in,
                              void* d_out, int out_size, void* d_ws, size_t ws_size,
                              hipStream_t stream){
    const int*   src   = (const int*)d_in[0];
    const int*   dst   = (const int*)d_in[1];
    const int*   etype = (const int*)d_in[2];
    const float* norm  = (const float*)d_in[3];
    const float* emb   = (const float*)d_in[4];
    const float* V1    = (const float*)d_in[5];
    const float* comp1 = (const float*)d_in[6];
    const float* bias1 = (const float*)d_in[7];
    const float* V2    = (const float*)d_in[8];
    const float* comp2 = (const float*)d_in[9];
    const float* bias2 = (const float*)d_in[10];
    float* out = (float*)d_out;

    char* w = (char*)d_ws;
    auto alloc = [&](size_t bytes) -> char* {
        char* p = w; w += (bytes + 255) & ~(size_t)255; return p;
    };
    int*      offsets = (int*)alloc((NN + 1) * 4);
    int*      counts  = (int*)alloc(NN * 4);
    int*      cursor  = (int*)alloc(NN * 4);
    int*      tot     = (int*)alloc(SC_B * 4);
    int4*     meta    = (int4*)alloc((size_t)EE * 16);
    ushort_t* Wt1     = (ushort_t*)alloc((size_t)HH * KK * 2);
    ushort_t* Wt2     = (ushort_t*)alloc((size_t)OUTD * KK * 2);
    ushort_t* xb      = (ushort_t*)alloc((size_t)NN * HH * 2);
    ushort_t* h       = (ushort_t*)alloc((size_t)NN * HH * 2);

    // CSR build + payload sort + weight/emb conversion
    zero_i32<<<(NN + 255)/256, 256, 0, stream>>>(counts, NN);
    hist_kernel<<<(EE + 255)/256, 256, 0, stream>>>(dst, counts);
    scan_part<<<SC_B, 256, 0, stream>>>(counts, tot);
    scan_tot<<<1, 64, 0, stream>>>(tot);
    scan_final<<<SC_B, 256, 0, stream>>>(counts, tot, offsets, cursor);
    scatter_kernel<<<(EE + 255)/256, 256, 0, stream>>>(dst, src, etype, norm, cursor, meta);
    convw_kernel<<<((HH + OUTD)*KK + 255)/256, 256, 0, stream>>>(V1, V2, Wt1, Wt2);
    conv_emb<<<(NN*HH/2 + 255)/256, 256, 0, stream>>>(emb, xb);

    int nblocks = NN / NPB;  // 3125 exact
    // layer 1: xb (bf16) -> h (bf16, relu)
    fused_layer<HH, true, true><<<nblocks, 1024, 0, stream>>>(
        xb, meta, offsets, comp1, Wt1, bias1, h);
    // layer 2: h (bf16) -> out (f32)
    fused_layer<OUTD, false, false><<<nblocks, 1024, 0, stream>>>(
        h, meta, offsets, comp2, Wt2, bias2, out);
}